// Round 4
// baseline (921.104 us; speedup 1.0000x reference)
//
#include <hip/hip_runtime.h>
#include <hip/hip_bf16.h>

// Problem constants (match reference setup_inputs)
#define N_CONV   4
#define C_IN     64
#define FILTERS  128
#define P_TOTAL  (8 * 256 * 256)   // 524288 pixels

typedef short bf16x8 __attribute__((ext_vector_type(8)));
typedef float f32x4  __attribute__((ext_vector_type(4)));

static __device__ __forceinline__ short f2bf(float f) {
    __hip_bfloat16 h = __float2bfloat16(f);   // RNE
    return *reinterpret_cast<short*>(&h);
}

// ---------------------------------------------------------------------------
// Pre-pack W (fp32 [4][64][128]) into bf16 MFMA A-fragment layout in d_ws.
// frag id = (n*2 + kt)*8 + ft.  Lane l, elem j holds:
//   A[row = f = ft*16 + (l&15)][k = kt*32 + (l>>4)*8 + j]  = W[n][k][f]
// (Internal k-order doesn't matter: A and B use the same convention.)
// ---------------------------------------------------------------------------
__global__ void prep_w_kernel(const float* __restrict__ W,
                              bf16x8* __restrict__ wp) {
    int t    = blockIdx.x * 256 + threadIdx.x;  // 4096 threads total
    int lane = t & 63;
    int frag = t >> 6;                          // 0..63
    int ft   = frag & 7;
    int kt   = (frag >> 3) & 1;
    int n    = frag >> 4;
    int f    = ft * 16 + (lane & 15);
    int c0   = kt * 32 + (lane >> 4) * 8;
    bf16x8 v;
    #pragma unroll
    for (int j = 0; j < 8; ++j)
        v[j] = f2bf(W[(n * C_IN + c0 + j) * FILTERS + f]);
    wp[(size_t)frag * 64 + lane] = v;
}

// ---------------------------------------------------------------------------
// Main kernel: one wave = 64 pixels x 128 filters x 4 convs.
// x loaded ONCE into register B-frags; W frags register-held per n.
// NEW: LDS store-transpose epilogue — MFMA D-layout scatter (16x64B segments)
// is rearranged through a per-wave 8KiB swizzled LDS region so every global
// store instruction writes 1KiB fully contiguous (the fillBuffer pattern that
// achieves 81% of HBM peak at <1 wave/SIMD).
// ---------------------------------------------------------------------------
__global__ __launch_bounds__(256, 2)
void nconv_mfma_kernel(const float* __restrict__ x,
                       const float* __restrict__ bias,
                       const bf16x8* __restrict__ wp,
                       float* __restrict__ out) {
    __shared__ f32x4 lds[4][16][32];   // [wave][px][f-chunk, XOR-swizzled] 32 KiB

    const int  tid  = threadIdx.x;
    const int  lane = tid & 63;
    const int  widb = tid >> 6;        // wave within block
    const int  wid  = (blockIdx.x * 256 + tid) >> 6;
    const int  lrow = lane & 15;       // B col -> pixel within sub-tile
    const int  lgrp = lane >> 4;       // k-group / D row-group
    const long px0  = (long)wid * 64;

    // B-frags for 4 sub-tiles of 16 px: x[px][c], 8 contiguous c per (lgrp,kt).
    bf16x8 xb[4][2];
    #pragma unroll
    for (int s = 0; s < 4; ++s) {
        const float* xp = x + (px0 + s * 16 + lrow) * C_IN + lgrp * 8;
        #pragma unroll
        for (int kt = 0; kt < 2; ++kt) {
            float4 a = *(const float4*)(xp + kt * 32);
            float4 b = *(const float4*)(xp + kt * 32 + 4);
            bf16x8 v;
            v[0] = f2bf(a.x); v[1] = f2bf(a.y); v[2] = f2bf(a.z); v[3] = f2bf(a.w);
            v[4] = f2bf(b.x); v[5] = f2bf(b.y); v[6] = f2bf(b.z); v[7] = f2bf(b.w);
            xb[s][kt] = v;
        }
    }

    #pragma unroll 1   // keep n-loop rolled: wf[16] lifetime stays within one n
    for (int n = 0; n < N_CONV; ++n) {
        // W frags for this n: 16 x 16B, register-held, reused by 4 sub-tiles.
        bf16x8 wf[16];
        #pragma unroll
        for (int ft = 0; ft < 8; ++ft)
            #pragma unroll
            for (int kt = 0; kt < 2; ++kt)
                wf[ft * 2 + kt] = wp[(size_t)((n * 2 + kt) * 8 + ft) * 64 + lane];

        #pragma unroll 1
        for (int s = 0; s < 4; ++s) {
            f32x4 acc[8];
            #pragma unroll
            for (int ft = 0; ft < 8; ++ft) acc[ft] = (f32x4){0.f, 0.f, 0.f, 0.f};

            #pragma unroll
            for (int ft = 0; ft < 8; ++ft)
                #pragma unroll
                for (int kt = 0; kt < 2; ++kt)
                    acc[ft] = __builtin_amdgcn_mfma_f32_16x16x32_bf16(
                        wf[ft * 2 + kt], xb[s][kt], acc[ft], 0, 0, 0);

            // Epilogue 1: bias + relu, write to swizzled per-wave LDS.
            // D layout: col = lane&15 = pixel, row = lgrp*4 + reg = f in ftile.
            // LDS chunk index c = f/4 = ft*4+lgrp, swizzled by px&7.
            #pragma unroll
            for (int ft = 0; ft < 8; ++ft) {
                float4 bv = *(const float4*)(bias + n * FILTERS + ft * 16 + lgrp * 4);
                f32x4 v;
                v[0] = fmaxf(acc[ft][0] + bv.x, 0.f);
                v[1] = fmaxf(acc[ft][1] + bv.y, 0.f);
                v[2] = fmaxf(acc[ft][2] + bv.z, 0.f);
                v[3] = fmaxf(acc[ft][3] + bv.w, 0.f);
                lds[widb][lrow][(ft * 4 + lgrp) ^ (lrow & 7)] = v;
            }

            // Epilogue 2: pixel-major read-back, 1KiB-contiguous stores.
            f32x4* ob = (f32x4*)(out + ((long)n * P_TOTAL + px0 + s * 16) * FILTERS);
            #pragma unroll
            for (int i = 0; i < 8; ++i) {
                int px = 2 * i + (lane >> 5);
                int c  = (lane & 31) ^ (px & 7);
                ob[i * 64 + lane] = lds[widb][px][c];
            }
        }
    }
}

extern "C" void kernel_launch(void* const* d_in, const int* in_sizes, int n_in,
                              void* d_out, int out_size, void* d_ws, size_t ws_size,
                              hipStream_t stream) {
    const float* x    = (const float*)d_in[0];
    const float* Wt   = (const float*)d_in[1];
    const float* bias = (const float*)d_in[2];
    float* out        = (float*)d_out;
    bf16x8* wp        = (bf16x8*)d_ws;   // needs 64 KiB scratch

    prep_w_kernel<<<16, 256, 0, stream>>>(Wt, wp);

    const int waves = P_TOTAL / 64;            // 8192 wave-tasks, 64 px each
    const int grid  = waves / 4;               // 2048 blocks, 4 waves each
    nconv_mfma_kernel<<<grid, 256, 0, stream>>>(x, bias, wp, out);
}

// Round 5
// 236.809 us; speedup vs baseline: 3.8896x; 3.8896x over previous
//
#include <hip/hip_runtime.h>
#include <hip/hip_bf16.h>

// Problem constants (match reference setup_inputs)
#define N_CONV   4
#define C_IN     64
#define FILTERS  128
#define P_TOTAL  (8 * 256 * 256)   // 524288 pixels

typedef short bf16x8 __attribute__((ext_vector_type(8)));
typedef float f32x4  __attribute__((ext_vector_type(4)));

static __device__ __forceinline__ short f2bf(float f) {
    __hip_bfloat16 h = __float2bfloat16(f);   // RNE
    return *reinterpret_cast<short*>(&h);
}

// ---------------------------------------------------------------------------
// Pre-pack W (fp32 [4][64][128]) into bf16 MFMA A-fragment layout in d_ws.
// frag id = (n*2 + kt)*8 + ft.  Lane l, elem j holds:
//   A[row = f = ft*16 + (l&15)][k = kt*32 + (l>>4)*8 + j]  = W[n][k][f]
// ---------------------------------------------------------------------------
__global__ void prep_w_kernel(const float* __restrict__ W,
                              bf16x8* __restrict__ wp) {
    int t    = blockIdx.x * 256 + threadIdx.x;  // 4096 threads total
    int lane = t & 63;
    int frag = t >> 6;                          // 0..63
    int ft   = frag & 7;
    int kt   = (frag >> 3) & 1;
    int n    = frag >> 4;
    int f    = ft * 16 + (lane & 15);
    int c0   = kt * 32 + (lane >> 4) * 8;
    bf16x8 v;
    #pragma unroll
    for (int j = 0; j < 8; ++j)
        v[j] = f2bf(W[(n * C_IN + c0 + j) * FILTERS + f]);
    wp[(size_t)frag * 64 + lane] = v;
}

// --------------------------- pipeline stages -------------------------------
__device__ __forceinline__ void compute_tile(f32x4 (&acc)[8],
                                             const bf16x8 (&wf)[16],
                                             const bf16x8 (&xbs)[2]) {
    #pragma unroll
    for (int ft = 0; ft < 8; ++ft) acc[ft] = (f32x4){0.f, 0.f, 0.f, 0.f};
    #pragma unroll
    for (int ft = 0; ft < 8; ++ft)
        #pragma unroll
        for (int kt = 0; kt < 2; ++kt)
            acc[ft] = __builtin_amdgcn_mfma_f32_16x16x32_bf16(
                wf[ft * 2 + kt], xbs[kt], acc[ft], 0, 0, 0);
}

// bias + relu + swizzled ds_write into this wave's private buffer.
// D layout: col = lane&15 = pixel, row = lgrp*4 + reg = f within ftile.
__device__ __forceinline__ void stage_tile(f32x4 (*buf)[32],
                                           const f32x4 (&acc)[8],
                                           const f32x4 (&bvn)[8],
                                           int lrow, int lgrp) {
    #pragma unroll
    for (int ft = 0; ft < 8; ++ft) {
        f32x4 v;
        v[0] = fmaxf(acc[ft][0] + bvn[ft][0], 0.f);
        v[1] = fmaxf(acc[ft][1] + bvn[ft][1], 0.f);
        v[2] = fmaxf(acc[ft][2] + bvn[ft][2], 0.f);
        v[3] = fmaxf(acc[ft][3] + bvn[ft][3], 0.f);
        buf[lrow][(ft * 4 + lgrp) ^ (lrow & 7)] = v;
    }
}

// pixel-major read-back -> every global store writes 1KiB fully contiguous.
__device__ __forceinline__ void drain_tile(const f32x4 (*buf)[32],
                                           f32x4* __restrict__ ob, int lane) {
    #pragma unroll
    for (int i = 0; i < 8; ++i) {
        int px = 2 * i + (lane >> 5);
        int c  = (lane & 31) ^ (px & 7);
        ob[i * 64 + lane] = buf[px][c];
    }
}

// ---------------------------------------------------------------------------
// Main kernel: one wave = 64 pixels x 128 filters x 4 convs.
// x loaded ONCE into register B-frags; W frags + bias register-held per n.
// Store path: software-pipelined LDS transpose, double-buffered per-wave
// regions (no __syncthreads). Program order per n:
//   c(s0) w(b0) | c(s1) w(b1) | r(b0) | c(s2) w(b0) | r(b1) | c(s3) w(b1)
//   | r(b0) | r(b1)
// so every LDS RAW/WAR has a 16-MFMA or 8-ds_read block covering its latency,
// and global stores (1KiB contiguous each) stream continuously.
// ---------------------------------------------------------------------------
__global__ __launch_bounds__(256, 2)
void nconv_mfma_kernel(const float* __restrict__ x,
                       const float* __restrict__ bias,
                       const bf16x8* __restrict__ wp,
                       float* __restrict__ out) {
    __shared__ f32x4 lds[4][2][16][32];   // [wave][buf][px][chunk] = 64 KiB

    const int  tid  = threadIdx.x;
    const int  lane = tid & 63;
    const int  widb = tid >> 6;
    const int  wid  = (blockIdx.x * 256 + tid) >> 6;
    const int  lrow = lane & 15;   // B col -> pixel within sub-tile
    const int  lgrp = lane >> 4;   // k-group / D row-group
    const long px0  = (long)wid * 64;

    // B-frags for 4 sub-tiles of 16 px: x[px][c], 8 contiguous c per (lgrp,kt).
    bf16x8 xb[4][2];
    #pragma unroll
    for (int s = 0; s < 4; ++s) {
        const float* xp = x + (px0 + s * 16 + lrow) * C_IN + lgrp * 8;
        #pragma unroll
        for (int kt = 0; kt < 2; ++kt) {
            float4 a = *(const float4*)(xp + kt * 32);
            float4 b = *(const float4*)(xp + kt * 32 + 4);
            bf16x8 v;
            v[0] = f2bf(a.x); v[1] = f2bf(a.y); v[2] = f2bf(a.z); v[3] = f2bf(a.w);
            v[4] = f2bf(b.x); v[5] = f2bf(b.y); v[6] = f2bf(b.z); v[7] = f2bf(b.w);
            xb[s][kt] = v;
        }
    }

    f32x4 (*b0)[32] = lds[widb][0];
    f32x4 (*b1)[32] = lds[widb][1];

    #pragma unroll 1   // keep n-loop rolled: wf/bvn lifetime stays within one n
    for (int n = 0; n < N_CONV; ++n) {
        // W frags for this n: 16 x 16B, register-held, reused by 4 sub-tiles.
        bf16x8 wf[16];
        #pragma unroll
        for (int ft = 0; ft < 8; ++ft)
            #pragma unroll
            for (int kt = 0; kt < 2; ++kt)
                wf[ft * 2 + kt] = wp[(size_t)((n * 2 + kt) * 8 + ft) * 64 + lane];
        // bias, hoisted so no global-load latency sits in front of ds_writes
        f32x4 bvn[8];
        #pragma unroll
        for (int ft = 0; ft < 8; ++ft)
            bvn[ft] = *(const f32x4*)(bias + n * FILTERS + ft * 16 + lgrp * 4);

        f32x4* obase = (f32x4*)out + ((long)n * P_TOTAL + px0) * (FILTERS / 4);
        f32x4 acc[8];

        compute_tile(acc, wf, xb[0]);
        stage_tile(b0, acc, bvn, lrow, lgrp);

        compute_tile(acc, wf, xb[1]);
        stage_tile(b1, acc, bvn, lrow, lgrp);
        drain_tile(b0, obase + 0 * 16 * 32, lane);

        compute_tile(acc, wf, xb[2]);
        stage_tile(b0, acc, bvn, lrow, lgrp);
        drain_tile(b1, obase + 1 * 16 * 32, lane);

        compute_tile(acc, wf, xb[3]);
        stage_tile(b1, acc, bvn, lrow, lgrp);
        drain_tile(b0, obase + 2 * 16 * 32, lane);
        drain_tile(b1, obase + 3 * 16 * 32, lane);
    }
}

extern "C" void kernel_launch(void* const* d_in, const int* in_sizes, int n_in,
                              void* d_out, int out_size, void* d_ws, size_t ws_size,
                              hipStream_t stream) {
    const float* x    = (const float*)d_in[0];
    const float* Wt   = (const float*)d_in[1];
    const float* bias = (const float*)d_in[2];
    float* out        = (float*)d_out;
    bf16x8* wp        = (bf16x8*)d_ws;   // needs 64 KiB scratch

    prep_w_kernel<<<16, 256, 0, stream>>>(Wt, wp);

    const int waves = P_TOTAL / 64;            // 8192 wave-tasks, 64 px each
    const int grid  = waves / 4;               // 2048 blocks, 4 waves each
    nconv_mfma_kernel<<<grid, 256, 0, stream>>>(x, bias, wp, out);
}

// Round 6
// 221.602 us; speedup vs baseline: 4.1566x; 1.0686x over previous
//
#include <hip/hip_runtime.h>
#include <hip/hip_bf16.h>

// Problem constants (match reference setup_inputs)
#define N_CONV   4
#define C_IN     64
#define FILTERS  128
#define P_TOTAL  (8 * 256 * 256)   // 524288 pixels

typedef short bf16x8 __attribute__((ext_vector_type(8)));
typedef float f32x4  __attribute__((ext_vector_type(4)));

static __device__ __forceinline__ short f2bf(float f) {
    __hip_bfloat16 h = __float2bfloat16(f);   // RNE
    return *reinterpret_cast<short*>(&h);
}

// ---------------------------------------------------------------------------
// Pre-pack W (fp32 [4][64][128]) into bf16 MFMA A-fragment layout in d_ws.
// frag id = (n*2 + kt)*8 + ft.  Lane l, elem j holds:
//   A[row = f = ft*16 + (l&15)][k = kt*32 + (l>>4)*8 + j]  = W[n][k][f]
// ---------------------------------------------------------------------------
__global__ void prep_w_kernel(const float* __restrict__ W,
                              bf16x8* __restrict__ wp) {
    int t    = blockIdx.x * 256 + threadIdx.x;  // 4096 threads total
    int lane = t & 63;
    int frag = t >> 6;                          // 0..63
    int ft   = frag & 7;
    int kt   = (frag >> 3) & 1;
    int n    = frag >> 4;
    int f    = ft * 16 + (lane & 15);
    int c0   = kt * 32 + (lane >> 4) * 8;
    bf16x8 v;
    #pragma unroll
    for (int j = 0; j < 8; ++j)
        v[j] = f2bf(W[(n * C_IN + c0 + j) * FILTERS + f]);
    wp[(size_t)frag * 64 + lane] = v;
}

// --------------------------- pipeline stages -------------------------------
__device__ __forceinline__ void compute_tile(f32x4 (&acc)[8],
                                             const bf16x8 (&wf)[16],
                                             const bf16x8 (&xbs)[2]) {
    #pragma unroll
    for (int ft = 0; ft < 8; ++ft) acc[ft] = (f32x4){0.f, 0.f, 0.f, 0.f};
    #pragma unroll
    for (int ft = 0; ft < 8; ++ft)
        #pragma unroll
        for (int kt = 0; kt < 2; ++kt)
            acc[ft] = __builtin_amdgcn_mfma_f32_16x16x32_bf16(
                wf[ft * 2 + kt], xbs[kt], acc[ft], 0, 0, 0);
}

// bias + relu + swizzled ds_write into this wave's private buffer.
// D layout: col = lane&15 = pixel, row = lgrp*4 + reg = f within ftile.
__device__ __forceinline__ void stage_tile(f32x4 (*buf)[32],
                                           const f32x4 (&acc)[8],
                                           const f32x4 (&bvn)[8],
                                           int lrow, int lgrp) {
    #pragma unroll
    for (int ft = 0; ft < 8; ++ft) {
        f32x4 v;
        v[0] = fmaxf(acc[ft][0] + bvn[ft][0], 0.f);
        v[1] = fmaxf(acc[ft][1] + bvn[ft][1], 0.f);
        v[2] = fmaxf(acc[ft][2] + bvn[ft][2], 0.f);
        v[3] = fmaxf(acc[ft][3] + bvn[ft][3], 0.f);
        buf[lrow][(ft * 4 + lgrp) ^ (lrow & 7)] = v;
    }
}

// pixel-major read-back -> every global store writes 1KiB fully contiguous.
// Non-temporal: output is never re-read, don't allocate it in L2.
__device__ __forceinline__ void drain_tile(const f32x4 (*buf)[32],
                                           f32x4* __restrict__ ob, int lane) {
    #pragma unroll
    for (int i = 0; i < 8; ++i) {
        int px = 2 * i + (lane >> 5);
        int c  = (lane & 31) ^ (px & 7);
        __builtin_nontemporal_store(buf[px][c], &ob[i * 64 + lane]);
    }
}

// ---------------------------------------------------------------------------
// Main kernel: one wave = 64 pixels x 128 filters x 4 convs.
// x loaded ONCE into register B-frags; W frags + bias register-held per n.
// Store path: software-pipelined LDS transpose, double-buffered per-wave
// regions (no __syncthreads). 2-wave blocks (32 KiB LDS) -> 5 blocks/CU,
// non-integer resident-set turnover (4096/1280) so block starts self-stagger
// and the device-wide store stream stays gapless.
// ---------------------------------------------------------------------------
__global__ __launch_bounds__(128, 2)
void nconv_mfma_kernel(const float* __restrict__ x,
                       const float* __restrict__ bias,
                       const bf16x8* __restrict__ wp,
                       float* __restrict__ out) {
    __shared__ f32x4 lds[2][2][16][32];   // [wave][buf][px][chunk] = 32 KiB

    const int  tid  = threadIdx.x;
    const int  lane = tid & 63;
    const int  widb = tid >> 6;
    const int  wid  = (blockIdx.x * 128 + tid) >> 6;
    const int  lrow = lane & 15;   // B col -> pixel within sub-tile
    const int  lgrp = lane >> 4;   // k-group / D row-group
    const long px0  = (long)wid * 64;

    // B-frags for 4 sub-tiles of 16 px: x[px][c], 8 contiguous c per (lgrp,kt).
    bf16x8 xb[4][2];
    #pragma unroll
    for (int s = 0; s < 4; ++s) {
        const float* xp = x + (px0 + s * 16 + lrow) * C_IN + lgrp * 8;
        #pragma unroll
        for (int kt = 0; kt < 2; ++kt) {
            float4 a = *(const float4*)(xp + kt * 32);
            float4 b = *(const float4*)(xp + kt * 32 + 4);
            bf16x8 v;
            v[0] = f2bf(a.x); v[1] = f2bf(a.y); v[2] = f2bf(a.z); v[3] = f2bf(a.w);
            v[4] = f2bf(b.x); v[5] = f2bf(b.y); v[6] = f2bf(b.z); v[7] = f2bf(b.w);
            xb[s][kt] = v;
        }
    }

    f32x4 (*b0)[32] = lds[widb][0];
    f32x4 (*b1)[32] = lds[widb][1];

    #pragma unroll 1   // keep n-loop rolled: wf/bvn lifetime stays within one n
    for (int n = 0; n < N_CONV; ++n) {
        // W frags for this n: 16 x 16B, register-held, reused by 4 sub-tiles.
        bf16x8 wf[16];
        #pragma unroll
        for (int ft = 0; ft < 8; ++ft)
            #pragma unroll
            for (int kt = 0; kt < 2; ++kt)
                wf[ft * 2 + kt] = wp[(size_t)((n * 2 + kt) * 8 + ft) * 64 + lane];
        // bias, hoisted so no global-load latency sits in front of ds_writes
        f32x4 bvn[8];
        #pragma unroll
        for (int ft = 0; ft < 8; ++ft)
            bvn[ft] = *(const f32x4*)(bias + n * FILTERS + ft * 16 + lgrp * 4);

        f32x4* obase = (f32x4*)out + ((long)n * P_TOTAL + px0) * (FILTERS / 4);
        f32x4 acc[8];

        compute_tile(acc, wf, xb[0]);
        stage_tile(b0, acc, bvn, lrow, lgrp);

        compute_tile(acc, wf, xb[1]);
        stage_tile(b1, acc, bvn, lrow, lgrp);
        drain_tile(b0, obase + 0 * 16 * 32, lane);

        compute_tile(acc, wf, xb[2]);
        stage_tile(b0, acc, bvn, lrow, lgrp);
        drain_tile(b1, obase + 1 * 16 * 32, lane);

        compute_tile(acc, wf, xb[3]);
        stage_tile(b1, acc, bvn, lrow, lgrp);
        drain_tile(b0, obase + 2 * 16 * 32, lane);
        drain_tile(b1, obase + 3 * 16 * 32, lane);
    }
}

extern "C" void kernel_launch(void* const* d_in, const int* in_sizes, int n_in,
                              void* d_out, int out_size, void* d_ws, size_t ws_size,
                              hipStream_t stream) {
    const float* x    = (const float*)d_in[0];
    const float* Wt   = (const float*)d_in[1];
    const float* bias = (const float*)d_in[2];
    float* out        = (float*)d_out;
    bf16x8* wp        = (bf16x8*)d_ws;   // needs 64 KiB scratch

    prep_w_kernel<<<16, 256, 0, stream>>>(Wt, wp);

    const int waves = P_TOTAL / 64;            // 8192 wave-tasks, 64 px each
    const int grid  = waves / 2;               // 4096 blocks, 2 waves each
    nconv_mfma_kernel<<<grid, 128, 0, stream>>>(x, bias, wp, out);
}

// Round 7
// 218.002 us; speedup vs baseline: 4.2252x; 1.0165x over previous
//
#include <hip/hip_runtime.h>
#include <hip/hip_bf16.h>

// Problem constants (match reference setup_inputs)
#define N_CONV   4
#define C_IN     64
#define FILTERS  128
#define P_TOTAL  (8 * 256 * 256)   // 524288 pixels

typedef short bf16x8 __attribute__((ext_vector_type(8)));
typedef float f32x4  __attribute__((ext_vector_type(4)));

static __device__ __forceinline__ short f2bf(float f) {
    __hip_bfloat16 h = __float2bfloat16(f);   // RNE
    return *reinterpret_cast<short*>(&h);
}

// ---------------------------------------------------------------------------
// Pre-pack W (fp32 [4][64][128]) into bf16 MFMA A-fragment layout in d_ws.
// frag id = (n*2 + kt)*8 + ft.  Lane l, elem j holds:
//   A[row = f = ft*16 + (l&15)][k = kt*32 + (l>>4)*8 + j]  = W[n][k][f]
// ---------------------------------------------------------------------------
__global__ void prep_w_kernel(const float* __restrict__ W,
                              bf16x8* __restrict__ wp) {
    int t    = blockIdx.x * 256 + threadIdx.x;  // 4096 threads total
    int lane = t & 63;
    int frag = t >> 6;                          // 0..63
    int ft   = frag & 7;
    int kt   = (frag >> 3) & 1;
    int n    = frag >> 4;
    int f    = ft * 16 + (lane & 15);
    int c0   = kt * 32 + (lane >> 4) * 8;
    bf16x8 v;
    #pragma unroll
    for (int j = 0; j < 8; ++j)
        v[j] = f2bf(W[(n * C_IN + c0 + j) * FILTERS + f]);
    wp[(size_t)frag * 64 + lane] = v;
}

// --------------------------- pipeline stages -------------------------------
__device__ __forceinline__ void compute_tile(f32x4 (&acc)[8],
                                             const bf16x8 (&wf)[16],
                                             const bf16x8 (&xbs)[2]) {
    #pragma unroll
    for (int ft = 0; ft < 8; ++ft) acc[ft] = (f32x4){0.f, 0.f, 0.f, 0.f};
    #pragma unroll
    for (int ft = 0; ft < 8; ++ft)
        #pragma unroll
        for (int kt = 0; kt < 2; ++kt)
            acc[ft] = __builtin_amdgcn_mfma_f32_16x16x32_bf16(
                wf[ft * 2 + kt], xbs[kt], acc[ft], 0, 0, 0);
}

// bias + relu + swizzled ds_write into this wave's private buffer.
// D layout: col = lane&15 = pixel, row = lgrp*4 + reg = f within ftile.
__device__ __forceinline__ void stage_tile(f32x4 (*buf)[32],
                                           const f32x4 (&acc)[8],
                                           const f32x4 (&bvn)[8],
                                           int lrow, int lgrp) {
    #pragma unroll
    for (int ft = 0; ft < 8; ++ft) {
        f32x4 v;
        v[0] = fmaxf(acc[ft][0] + bvn[ft][0], 0.f);
        v[1] = fmaxf(acc[ft][1] + bvn[ft][1], 0.f);
        v[2] = fmaxf(acc[ft][2] + bvn[ft][2], 0.f);
        v[3] = fmaxf(acc[ft][3] + bvn[ft][3], 0.f);
        buf[lrow][(ft * 4 + lgrp) ^ (lrow & 7)] = v;
    }
}

// pixel-major read-back -> every global store writes 1KiB fully contiguous.
// Non-temporal: output is never re-read, don't allocate it in cache.
__device__ __forceinline__ void drain_tile(const f32x4 (*buf)[32],
                                           f32x4* __restrict__ ob, int lane) {
    #pragma unroll
    for (int i = 0; i < 8; ++i) {
        int px = 2 * i + (lane >> 5);
        int c  = (lane & 31) ^ (px & 7);
        __builtin_nontemporal_store(buf[px][c], &ob[i * 64 + lane]);
    }
}

// ---------------------------------------------------------------------------
// Main kernel: PERSISTENT waves. 2048 waves, each owns exactly 4 consecutive
// 64-px tiles (8192/2048 = 4.0, no tail) — one dispatch sweep, zero
// generation turnovers, so the device-wide store stream never collectively
// drains. Per tile: x -> register B-frags; per n: register-held W frags +
// bias; software-pipelined double-buffered LDS store-transpose (no
// __syncthreads) emitting 1KiB-contiguous nt stores.
// ---------------------------------------------------------------------------
__global__ __launch_bounds__(128, 2)
void nconv_mfma_kernel(const float* __restrict__ x,
                       const float* __restrict__ bias,
                       const bf16x8* __restrict__ wp,
                       float* __restrict__ out) {
    __shared__ f32x4 lds[2][2][16][32];   // [wave][buf][px][chunk] = 32 KiB

    const int  tid  = threadIdx.x;
    const int  lane = tid & 63;
    const int  widb = tid >> 6;
    const int  wid  = (blockIdx.x * 128 + tid) >> 6;   // 0..2047
    const int  lrow = lane & 15;   // B col -> pixel within sub-tile
    const int  lgrp = lane >> 4;   // k-group / D row-group

    f32x4 (*b0)[32] = lds[widb][0];
    f32x4 (*b1)[32] = lds[widb][1];

    #pragma unroll 1
    for (int t = 0; t < 4; ++t) {
        const long px0 = ((long)wid * 4 + t) * 64;   // consecutive tiles

        // B-frags for 4 sub-tiles of 16 px: x[px][c], 8 contiguous c each.
        bf16x8 xb[4][2];
        #pragma unroll
        for (int s = 0; s < 4; ++s) {
            const float* xp = x + (px0 + s * 16 + lrow) * C_IN + lgrp * 8;
            #pragma unroll
            for (int kt = 0; kt < 2; ++kt) {
                float4 a = *(const float4*)(xp + kt * 32);
                float4 b = *(const float4*)(xp + kt * 32 + 4);
                bf16x8 v;
                v[0] = f2bf(a.x); v[1] = f2bf(a.y); v[2] = f2bf(a.z); v[3] = f2bf(a.w);
                v[4] = f2bf(b.x); v[5] = f2bf(b.y); v[6] = f2bf(b.z); v[7] = f2bf(b.w);
                xb[s][kt] = v;
            }
        }

        #pragma unroll 1   // keep n-loop rolled: wf/bvn lifetime within one n
        for (int n = 0; n < N_CONV; ++n) {
            // W frags for this n: 16 x 16B, register-held, reused by 4 sub-tiles.
            bf16x8 wf[16];
            #pragma unroll
            for (int ft = 0; ft < 8; ++ft)
                #pragma unroll
                for (int kt = 0; kt < 2; ++kt)
                    wf[ft * 2 + kt] = wp[(size_t)((n * 2 + kt) * 8 + ft) * 64 + lane];
            // bias, hoisted so no global-load latency fronts the ds_writes
            f32x4 bvn[8];
            #pragma unroll
            for (int ft = 0; ft < 8; ++ft)
                bvn[ft] = *(const f32x4*)(bias + n * FILTERS + ft * 16 + lgrp * 4);

            f32x4* obase = (f32x4*)out + ((long)n * P_TOTAL + px0) * (FILTERS / 4);
            f32x4 acc[8];

            compute_tile(acc, wf, xb[0]);
            stage_tile(b0, acc, bvn, lrow, lgrp);

            compute_tile(acc, wf, xb[1]);
            stage_tile(b1, acc, bvn, lrow, lgrp);
            drain_tile(b0, obase + 0 * 16 * 32, lane);

            compute_tile(acc, wf, xb[2]);
            stage_tile(b0, acc, bvn, lrow, lgrp);
            drain_tile(b1, obase + 1 * 16 * 32, lane);

            compute_tile(acc, wf, xb[3]);
            stage_tile(b1, acc, bvn, lrow, lgrp);
            drain_tile(b0, obase + 2 * 16 * 32, lane);
            drain_tile(b1, obase + 3 * 16 * 32, lane);
        }
    }
}

extern "C" void kernel_launch(void* const* d_in, const int* in_sizes, int n_in,
                              void* d_out, int out_size, void* d_ws, size_t ws_size,
                              hipStream_t stream) {
    const float* x    = (const float*)d_in[0];
    const float* Wt   = (const float*)d_in[1];
    const float* bias = (const float*)d_in[2];
    float* out        = (float*)d_out;
    bf16x8* wp        = (bf16x8*)d_ws;   // needs 64 KiB scratch

    prep_w_kernel<<<16, 256, 0, stream>>>(Wt, wp);

    // 1024 blocks x 2 waves = 2048 persistent waves; 4 tiles each, no tail.
    nconv_mfma_kernel<<<1024, 128, 0, stream>>>(x, bias, wp, out);
}